// Round 1
// baseline (99.726 us; speedup 1.0000x reference)
//
#include <hip/hip_runtime.h>
#include <hip/hip_bf16.h>
#include <math.h>

// Problem constants (from reference): B=4096, C=32768, L=8192, K=64
#define BB 4096
#define CC 32768
#define KK 64

// Per-row kernel: one block (256 threads = 4 waves) per batch row.
// Computes loss term for row b into ws[b]:
//   term = is_cluster ? log(p_label + neigh_sum) : log(p_label)   (in log-space, no softmax materialized)
__global__ __launch_bounds__(256) void row_loss_kernel(
    const float* __restrict__ x,
    const int* __restrict__ y,
    const int* __restrict__ position,
    const int* __restrict__ neighbours,
    const void* __restrict__ mask_raw,
    float* __restrict__ row_out) {
  const int b = blockIdx.x;
  const int t = threadIdx.x;
  const int lane = t & 63;
  const int wv = t >> 6;

  const float4* row = reinterpret_cast<const float4*>(x + (size_t)b * CC);

  // ---- online max/sum-exp over this thread's 128 elements (32 float4s) ----
  float m = -1e30f;
  float s = 0.f;
#pragma unroll 8
  for (int i = 0; i < 32; ++i) {
    float4 v = row[t + i * 256];
    float vm = fmaxf(fmaxf(v.x, v.y), fmaxf(v.z, v.w));
    float nm = fmaxf(m, vm);
    s = s * __expf(m - nm) +
        (__expf(v.x - nm) + __expf(v.y - nm)) +
        (__expf(v.z - nm) + __expf(v.w - nm));
    m = nm;
  }

  // ---- wave butterfly combine of (m, s) ----
  for (int off = 32; off; off >>= 1) {
    float om = __shfl_xor(m, off);
    float os = __shfl_xor(s, off);
    float nm = fmaxf(m, om);
    s = s * __expf(m - nm) + os * __expf(om - nm);
    m = nm;
  }

  // ---- cross-wave combine via LDS (4 waves) ----
  __shared__ float sm[4], ss[4];
  if (lane == 0) { sm[wv] = m; ss[wv] = s; }
  __syncthreads();
  float M = sm[0], S = ss[0];
#pragma unroll
  for (int w = 1; w < 4; ++w) {
    float om = sm[w], os = ss[w];
    float nm = fmaxf(M, om);
    S = S * __expf(M - nm) + os * __expf(om - nm);
    M = nm;
  }
  const float lse = M + __logf(S);

  // ---- tail: label prob + neighbour gather (wave 0 only) ----
  if (wv == 0) {
    const int yb = y[b];
    const int p = position[yb];
    const float xy = x[(size_t)b * CC + yb];

    if (p < 0) {
      if (lane == 0) row_out[b] = xy - lse;
    } else {
      // Detect how the bool mask was marshalled: float32 / 1-byte / int32.
      // float mode: words are 0 or 0x3F800000. byte mode: packed 0/1 bytes
      // (words frequently >1, never ==0x3F800000). int mode: words 0/1.
      const unsigned int* mw = reinterpret_cast<const unsigned int*>(mask_raw);
      const unsigned int w0 = mw[lane];
      const bool is_float = __ballot(w0 == 0x3F800000u) != 0ull;
      const bool is_byte  = !is_float && (__ballot(w0 > 1u) != 0ull);

      const size_t mi = (size_t)p * KK + lane;
      bool valid;
      if (is_float)      valid = reinterpret_cast<const float*>(mask_raw)[mi] != 0.f;
      else if (is_byte)  valid = reinterpret_cast<const unsigned char*>(mask_raw)[mi] != 0;
      else               valid = reinterpret_cast<const int*>(mask_raw)[mi] != 0;

      const int idx = neighbours[mi];
      const float xv = valid ? x[(size_t)b * CC + idx] : -INFINITY;

      // stable log(exp(xy) + sum_valid exp(xv))
      float mx = xv;
      for (int off = 32; off; off >>= 1) mx = fmaxf(mx, __shfl_xor(mx, off));
      const float nm = fmaxf(mx, xy);
      float e = valid ? __expf(xv - nm) : 0.f;
      for (int off = 32; off; off >>= 1) e += __shfl_xor(e, off);
      const float tsum = e + __expf(xy - nm);
      if (lane == 0) row_out[b] = nm + __logf(tsum) - lse;
    }
  }
}

// Deterministic final reduce: sum 4096 per-row terms, scale, negate.
__global__ __launch_bounds__(256) void finalize_kernel(
    const float* __restrict__ row_out, float* __restrict__ out) {
  const int t = threadIdx.x;
  float acc = 0.f;
#pragma unroll
  for (int i = 0; i < BB / 256; ++i) acc += row_out[t + i * 256];
  for (int off = 32; off; off >>= 1) acc += __shfl_xor(acc, off);
  __shared__ float ws[4];
  if ((t & 63) == 0) ws[t >> 6] = acc;
  __syncthreads();
  if (t == 0) out[0] = -(ws[0] + ws[1] + ws[2] + ws[3]) / (float)BB;
}

extern "C" void kernel_launch(void* const* d_in, const int* in_sizes, int n_in,
                              void* d_out, int out_size, void* d_ws, size_t ws_size,
                              hipStream_t stream) {
  const float* x          = reinterpret_cast<const float*>(d_in[0]);
  const int*   y          = reinterpret_cast<const int*>(d_in[1]);
  const int*   position   = reinterpret_cast<const int*>(d_in[2]);
  const int*   neighbours = reinterpret_cast<const int*>(d_in[3]);
  const void*  mask       = d_in[4];
  float* out = reinterpret_cast<float*>(d_out);
  float* ws  = reinterpret_cast<float*>(d_ws);

  row_loss_kernel<<<BB, 256, 0, stream>>>(x, y, position, neighbours, mask, ws);
  finalize_kernel<<<1, 256, 0, stream>>>(ws, out);
}